// Round 5
// baseline (857.373 us; speedup 1.0000x reference)
//
#include <hip/hip_runtime.h>

// ---------------------------------------------------------------------------
// MHSA (faithful: softmax over HEADS at each position).
//   cvt: fp32->bf16 for weights + activations
//   GEMM: 256x256 8-wave, m201-style 8-phase/2-barrier schedule:
//         phase = {ds_read subtile; stage half-tile; BAR; lgkm0; 16 MFMA; BAR}
//         counted vmcnt(4) once per K-tile (never 0 mid-loop)
//   attention: per-position 16x16 softmax-over-heads + PV, permuted scatter
// ---------------------------------------------------------------------------

#define DEV __device__ __forceinline__

using short8  = __attribute__((ext_vector_type(8))) short;
using ushort8 = __attribute__((ext_vector_type(8))) unsigned short;
using f32x4   = __attribute__((ext_vector_type(4))) float;
using u16x8   = __attribute__((ext_vector_type(8))) unsigned short;

constexpr int BATCH = 4, SEQ = 4096, DIM = 2048;
constexpr int GM = BATCH * SEQ;   // 16384
constexpr int GN = DIM, GK = DIM; // 2048

DEV unsigned short f2bf(float f) {
  unsigned int u = __builtin_bit_cast(unsigned int, f);
  u += 0x7FFFu + ((u >> 16) & 1u);   // RNE
  return (unsigned short)(u >> 16);
}
DEV float bf2f(unsigned short h) {
  unsigned int u = ((unsigned int)h) << 16;
  return __builtin_bit_cast(float, u);
}

DEV void gload16(const void* g, void* l) {
  __builtin_amdgcn_global_load_lds(
      (const __attribute__((address_space(1))) void*)g,
      (__attribute__((address_space(3))) void*)l, 16, 0, 0);
}

#define BAR    __builtin_amdgcn_s_barrier()
#define LGKM0  asm volatile("s_waitcnt lgkmcnt(0)" ::: "memory")
#define LGKM8  asm volatile("s_waitcnt lgkmcnt(8)" ::: "memory")
#define VMC(N) asm volatile("s_waitcnt vmcnt(" #N ")" ::: "memory")
#define SCHED0 __builtin_amdgcn_sched_barrier(0)
#define PRIO1  __builtin_amdgcn_s_setprio(1)
#define PRIO0  __builtin_amdgcn_s_setprio(0)
#define MFMA16(a, b, c) __builtin_amdgcn_mfma_f32_16x16x32_bf16(a, b, c, 0, 0, 0)

// ---------------- fp32 -> bf16 conversion ---------------------------------
__global__ void cvt_f32_bf16(const float* __restrict__ src,
                             unsigned short* __restrict__ dst, int n) {
  int i = (blockIdx.x * blockDim.x + threadIdx.x) * 4;
  if (i >= n) return;
  f32x4 f = *(const f32x4*)(src + i);
  ushort4 o;
  o.x = f2bf(f[0]); o.y = f2bf(f[1]); o.z = f2bf(f[2]); o.w = f2bf(f[3]);
  *(ushort4*)(dst + i) = o;
}

// ---------------- 256^2 8-wave 8-phase GEMM: C = A[M,K]*B[N,K]^T + bias ----
// LDS: As/Bs[2 dbuf][2 half][128x64] bf16 = 128 KiB, XOR-swizzle
// byte^=((row&7)<<4) within each 128B row (0 conflicts, proven R2-R4).
// K-tile T lives in dbuf (T&1). Stage schedule (one half-tile per phase):
//   P1: A-lo(T+1)->nb   P2: A-hi(T+1)->nb   P3: B-lo(T+2)->cb
//   P4: B-hi(T+2)->cb + vmcnt(4)
// Safety: each half staged in the phase AFTER its last ds_read phase
// (lgkm0-before-MFMA + end-of-phase barrier make all waves' reads complete).
template <bool OUTF32>
__global__ __launch_bounds__(512, 2)
void gemm256(const unsigned short* __restrict__ Ap,
             const unsigned short* __restrict__ Bp,
             const float* __restrict__ bias, void* __restrict__ Cp) {
  constexpr int BK = 64, KT = GK / BK;   // 32 K-tiles
  __shared__ unsigned short As[2][2][128 * 64];
  __shared__ unsigned short Bs[2][2][128 * 64];

  const int tid  = threadIdx.x;
  const int lane = tid & 63;
  const int wv   = tid >> 6;
  const int wm   = wv >> 2, wn = wv & 3;

  // XCD-chunked mapping (proven: FETCH 270->98 MB)
  int bid = (int)blockIdx.x;
  const int xcd = bid & 7, rr = bid >> 3;
  const int gg = rr >> 5, jj = rr & 31;
  const int mt = xcd * 8 + gg * 4 + (jj & 3);
  const int nt = jj >> 2;
  const int bm0 = mt * 256, bn0 = nt * 256;

  // staging geometry: dest byte d (linear) in 16KB half, src = unswizzle(d)
  int dst_[2];
  size_t offA_[2][2], offB_[2][2];   // [half][r]
#pragma unroll
  for (int r = 0; r < 2; ++r) {
    int d = tid * 16 + r * 8192;
    int s = d ^ (((d >> 7) & 7) << 4);
    int row = s >> 7, col = (s & 127) >> 1;
    dst_[r] = d;
#pragma unroll
    for (int h = 0; h < 2; ++h) {
      offA_[h][r] = (size_t)(bm0 + h * 128 + row) * GK + col;
      offB_[h][r] = (size_t)(bn0 + h * 128 + row) * GK + col;
    }
  }

  const int r16 = lane & 15, kb = (lane >> 4) * 16;
  const int bhalf = wn >> 1;
  const int brow0 = (wn & 1) * 64 + r16;

  f32x4 acc[8][4] = {};
  short8 af[4][2], bl[2][2], bh[2][2];

  auto stA = [&](int buf, int h, int T) {
#pragma unroll
    for (int r = 0; r < 2; ++r)
      gload16(Ap + offA_[h][r] + (size_t)T * BK, (char*)&As[buf][h][0] + dst_[r]);
  };
  auto stB = [&](int buf, int h, int T) {
#pragma unroll
    for (int r = 0; r < 2; ++r)
      gload16(Bp + offB_[h][r] + (size_t)T * BK, (char*)&Bs[buf][h][0] + dst_[r]);
  };
  auto ldf = [&](const unsigned short* base, int rowh, int ks) -> short8 {
    int a = (rowh * 128 + ks * 64 + kb) ^ ((rowh & 7) << 4);
    return *(const short8*)((const char*)base + a);
  };

  // ---- prologue: tile0 (4 halves) -> buf0; B halves of tile1 -> buf1 ----
  stA(0, 0, 0); stA(0, 1, 0);
  stB(0, 0, 0); stB(0, 1, 0);
  stB(1, 0, 1); stB(1, 1, 1);
  VMC(4);   // tile0 resident; B(1) in flight
  BAR;

  for (int T = 0; T < KT; ++T) {
    const int bb = T & 1;
    const unsigned short* Abase = &As[bb][wm][0];
    const unsigned short* Bbase = &Bs[bb][bhalf][0];
    const bool m1 = (T + 1 < KT), m2 = (T + 2 < KT);

    // ===== P1: Q(mlo,nlo) =====
#pragma unroll
    for (int m = 0; m < 4; ++m) {
      af[m][0] = ldf(Abase, m * 16 + r16, 0);
      af[m][1] = ldf(Abase, m * 16 + r16, 1);
    }
#pragma unroll
    for (int n = 0; n < 2; ++n) {
      bl[n][0] = ldf(Bbase, brow0 + n * 16, 0);
      bl[n][1] = ldf(Bbase, brow0 + n * 16, 1);
    }
    if (m1) stA(bb ^ 1, 0, T + 1);
    LGKM8; SCHED0; BAR; LGKM0; SCHED0;
    PRIO1;
#pragma unroll
    for (int m = 0; m < 4; ++m)
#pragma unroll
      for (int n = 0; n < 2; ++n) {
        acc[m][n] = MFMA16(af[m][0], bl[n][0], acc[m][n]);
        acc[m][n] = MFMA16(af[m][1], bl[n][1], acc[m][n]);
      }
    PRIO0; SCHED0; BAR;

    // ===== P2: Q(mlo,nhi) =====
#pragma unroll
    for (int n = 0; n < 2; ++n) {
      bh[n][0] = ldf(Bbase, brow0 + 32 + n * 16, 0);
      bh[n][1] = ldf(Bbase, brow0 + 32 + n * 16, 1);
    }
    if (m1) stA(bb ^ 1, 1, T + 1);
    SCHED0; BAR; LGKM0; SCHED0;
    PRIO1;
#pragma unroll
    for (int m = 0; m < 4; ++m)
#pragma unroll
      for (int n = 0; n < 2; ++n) {
        acc[m][2 + n] = MFMA16(af[m][0], bh[n][0], acc[m][2 + n]);
        acc[m][2 + n] = MFMA16(af[m][1], bh[n][1], acc[m][2 + n]);
      }
    PRIO0; SCHED0; BAR;

    // ===== P3: Q(mhi,nhi) =====
#pragma unroll
    for (int m = 0; m < 4; ++m) {
      af[m][0] = ldf(Abase, 64 + m * 16 + r16, 0);
      af[m][1] = ldf(Abase, 64 + m * 16 + r16, 1);
    }
    if (m2) stB(bb, 0, T + 2);
    SCHED0; BAR; LGKM0; SCHED0;
    PRIO1;
#pragma unroll
    for (int m = 0; m < 4; ++m)
#pragma unroll
      for (int n = 0; n < 2; ++n) {
        acc[4 + m][2 + n] = MFMA16(af[m][0], bh[n][0], acc[4 + m][2 + n]);
        acc[4 + m][2 + n] = MFMA16(af[m][1], bh[n][1], acc[4 + m][2 + n]);
      }
    PRIO0; SCHED0; BAR;

    // ===== P4: Q(mhi,nlo) =====
    if (m2) {
      stB(bb, 1, T + 2);
      SCHED0; VMC(4);   // drain through A(T+1); B(T+2) halves fly
    } else {
      SCHED0; VMC(0);   // tail: drain everything (A(T+1) at T=KT-2)
    }
    SCHED0; BAR;
    PRIO1;
#pragma unroll
    for (int m = 0; m < 4; ++m)
#pragma unroll
      for (int n = 0; n < 2; ++n) {
        acc[4 + m][n] = MFMA16(af[m][0], bl[n][0], acc[4 + m][n]);
        acc[4 + m][n] = MFMA16(af[m][1], bl[n][1], acc[4 + m][n]);
      }
    PRIO0; SCHED0; BAR;
  }

  // ---- epilogue: C row=(lane>>4)*4+i, col=lane&15 (m89-verified) ----
  float bs[4];
#pragma unroll
  for (int n = 0; n < 4; ++n) bs[n] = bias[bn0 + wn * 64 + n * 16 + r16];
  const int rb = (lane >> 4) * 4;
#pragma unroll
  for (int m = 0; m < 8; ++m)
#pragma unroll
    for (int i = 0; i < 4; ++i) {
      const size_t row = (size_t)bm0 + wm * 128 + m * 16 + rb + i;
#pragma unroll
      for (int n = 0; n < 4; ++n) {
        const int col = bn0 + wn * 64 + n * 16 + r16;
        float v = acc[m][n][i] + bs[n];
        if constexpr (OUTF32)
          ((float*)Cp)[row * GN + col] = v;
        else
          ((unsigned short*)Cp)[row * GN + col] = f2bf(v);
      }
    }
}

// ---------------- per-position attention (softmax over heads) -------------
__global__ __launch_bounds__(256)
void attn_kernel(const unsigned short* __restrict__ Qb,
                 const unsigned short* __restrict__ Kb,
                 const unsigned short* __restrict__ Vb,
                 float* __restrict__ attnOut,
                 unsigned short* __restrict__ X2) {
  __shared__ float qf[16 * 128];
  __shared__ float kf[16 * 132];
  __shared__ float vf[16 * 128];
  __shared__ float sc[256];

  const int t = threadIdx.x;
  const int p = blockIdx.x;
  const size_t rowoff = (size_t)p * DIM;

  {
    const int e = t * 8;
    u16x8 qv = *(const u16x8*)(Qb + rowoff + e);
    u16x8 kv = *(const u16x8*)(Kb + rowoff + e);
    u16x8 vv = *(const u16x8*)(Vb + rowoff + e);
    const int r = t >> 4, c = (t & 15) * 8;
#pragma unroll
    for (int j = 0; j < 8; ++j) qf[r * 128 + c + j] = bf2f(qv[j]);
#pragma unroll
    for (int j = 0; j < 8; ++j) kf[r * 132 + c + j] = bf2f(kv[j]);
#pragma unroll
    for (int j = 0; j < 8; ++j) vf[r * 128 + c + j] = bf2f(vv[j]);
  }
  __syncthreads();

  const int i = t >> 4, j = t & 15;
  float s = 0.f;
#pragma unroll
  for (int d4 = 0; d4 < 32; ++d4) {
    f32x4 q4 = *(const f32x4*)&qf[i * 128 + d4 * 4];
    f32x4 k4 = *(const f32x4*)&kf[j * 132 + d4 * 4];
    s = fmaf(q4[0], k4[0], fmaf(q4[1], k4[1], fmaf(q4[2], k4[2], fmaf(q4[3], k4[3], s))));
  }
  s *= 0.08838834764831845f;

  float mx = s;
#pragma unroll
  for (int off = 8; off; off >>= 1) mx = fmaxf(mx, __shfl_xor(mx, off, 16));
  float ex = __expf(s - mx);
  float sum = ex;
#pragma unroll
  for (int off = 8; off; off >>= 1) sum += __shfl_xor(sum, off, 16);
  float a = ex / sum;

  attnOut[(size_t)p * 256 + t] = a;
  sc[t] = a;
  __syncthreads();

  const int dh0 = j * 8;
  float o[8] = {};
#pragma unroll
  for (int jjq = 0; jjq < 16; ++jjq) {
    float aij = sc[i * 16 + jjq];
#pragma unroll
    for (int e2 = 0; e2 < 8; ++e2)
      o[e2] = fmaf(aij, vf[jjq * 128 + dh0 + e2], o[e2]);
  }
  const int b = p >> 12, spos = p & 4095;
  const int row = i * 256 + (spos >> 4);
  const int col = ((spos & 15) << 7) + dh0;
  ushort8 pk;
#pragma unroll
  for (int e2 = 0; e2 < 8; ++e2) pk[e2] = f2bf(o[e2]);
  *(ushort8*)(X2 + (size_t)b * (SEQ * DIM) + (size_t)row * DIM + col) = pk;
}

// ---------------------------------------------------------------------------
extern "C" void kernel_launch(void* const* d_in, const int* in_sizes, int n_in,
                              void* d_out, int out_size, void* d_ws,
                              size_t ws_size, hipStream_t stream) {
  const float* q  = (const float*)d_in[0];
  const float* k  = (const float*)d_in[1];
  const float* v  = (const float*)d_in[2];
  const float* Wq = (const float*)d_in[3];
  const float* bq = (const float*)d_in[4];
  const float* Wk = (const float*)d_in[5];
  const float* bk = (const float*)d_in[6];
  const float* Wv = (const float*)d_in[7];
  const float* bv = (const float*)d_in[8];
  const float* Wo = (const float*)d_in[9];
  const float* bo = (const float*)d_in[10];

  const size_t NE = (size_t)GM * GK;  // 33,554,432
  const size_t WE = (size_t)GK * GN;  //  4,194,304

  unsigned short* ws16 = (unsigned short*)d_ws;
  unsigned short* Wq_b = ws16;
  unsigned short* Wk_b = Wq_b + WE;
  unsigned short* Wv_b = Wk_b + WE;
  unsigned short* Wo_b = Wv_b + WE;
  unsigned short* Qb   = Wo_b + WE;
  unsigned short* Kb   = Qb + NE;
  unsigned short* Vb   = Kb + NE;
  unsigned short* X2   = Vb + NE;
  unsigned short* Qin  = X2 + NE;
  unsigned short* Kin  = Qin + NE;
  unsigned short* Vin  = Kin + NE;

  float* outMain = (float*)d_out;
  float* attnOut = outMain + (size_t)GM * GN;

  cvt_f32_bf16<<<WE / 1024, 256, 0, stream>>>(Wq, Wq_b, (int)WE);
  cvt_f32_bf16<<<WE / 1024, 256, 0, stream>>>(Wk, Wk_b, (int)WE);
  cvt_f32_bf16<<<WE / 1024, 256, 0, stream>>>(Wv, Wv_b, (int)WE);
  cvt_f32_bf16<<<WE / 1024, 256, 0, stream>>>(Wo, Wo_b, (int)WE);

  cvt_f32_bf16<<<NE / 1024, 256, 0, stream>>>(q, Qin, (int)NE);
  cvt_f32_bf16<<<NE / 1024, 256, 0, stream>>>(k, Kin, (int)NE);
  cvt_f32_bf16<<<NE / 1024, 256, 0, stream>>>(v, Vin, (int)NE);

  constexpr int G256 = (GM / 256) * (GN / 256);   // 512

  gemm256<false><<<G256, 512, 0, stream>>>(Qin, Wq_b, bq, Qb);
  gemm256<false><<<G256, 512, 0, stream>>>(Kin, Wk_b, bk, Kb);
  gemm256<false><<<G256, 512, 0, stream>>>(Vin, Wv_b, bv, Vb);

  attn_kernel<<<GM, 256, 0, stream>>>(Qb, Kb, Vb, attnOut, X2);

  gemm256<true><<<G256, 512, 0, stream>>>(X2, Wo_b, bo, outMain);
}